// Round 3
// baseline (272.513 us; speedup 1.0000x reference)
//
#include <hip/hip_runtime.h>
#include <hip/hip_fp16.h>

#define FH 200
#define FW 200
#define FHW 40000
#define FC 256
#define NBIN 49        // 7*7 output bins
#define NSAMP 196      // NBIN * 4 subsamples
#define OH_STRIDE 136  // out_h [bin][ch] stride in halves: 272 B, 16B-multiple

// ---------------------------------------------------------------------------
// Per-sample geometry: weights (pre-multiplied by valid-mask and 0.25 mean
// factor) and 4 bilinear-corner offsets (elements of the chosen layout).
// Matches the JAX reference (aligned coords, clamp-at-edge, valid in [-1,H]).
// ---------------------------------------------------------------------------
__device__ __forceinline__ void compute_sample(const float* __restrict__ roi,
                                               int s, bool nhwc,
                                               float4* wout, int4* oout)
{
    int   b  = (int)roi[0];
    float cw = roi[1] * 0.25f - 0.5f;
    float ch = roi[2] * 0.25f - 0.5f;
    float rw = fmaxf(roi[3] * 0.25f, 1.0f);
    float rh = fmaxf(roi[4] * 0.25f, 1.0f);
    float th = roi[5] * 0.017453292519943295f;   // pi/180
    float ct = cosf(th);
    float st = sinf(th);
    float bin_h = rh / 7.0f;
    float bin_w = rw / 7.0f;

    int bin = s >> 2;
    int sub = s & 3;
    int iy  = sub >> 1;
    int ix  = sub & 1;
    int ph  = bin / 7;
    int pw  = bin - ph * 7;

    float fy = 0.25f + 0.5f * (float)iy;  // frac = {0.25, 0.75}
    float fx = 0.25f + 0.5f * (float)ix;
    float yy = -rh * 0.5f + ((float)ph + fy) * bin_h;
    float xx = -rw * 0.5f + ((float)pw + fx) * bin_w;
    float y  = yy * ct - xx * st + ch;
    float x  = yy * st + xx * ct + cw;

    bool valid = (y >= -1.0f) && (y <= (float)FH) && (x >= -1.0f) && (x <= (float)FW);
    y = fmaxf(y, 0.0f);
    x = fmaxf(x, 0.0f);
    int y0 = (int)floorf(y);
    int x0 = (int)floorf(x);
    bool cy = (y0 >= FH - 1);
    bool cx = (x0 >= FW - 1);
    int ylo = cy ? (FH - 1) : y0;
    int yhi = cy ? (FH - 1) : (y0 + 1);
    int xlo = cx ? (FW - 1) : x0;
    int xhi = cx ? (FW - 1) : (x0 + 1);
    float ly = cy ? 0.0f : (y - (float)y0);
    float lx = cx ? 0.0f : (x - (float)x0);
    float hy = 1.0f - ly;
    float hx = 1.0f - lx;
    float m  = valid ? 0.25f : 0.0f;   // fold valid-mask + mean(4 samples)

    *wout = make_float4(hy * hx * m, hy * lx * m, ly * hx * m, ly * lx * m);

    int bb = b * (FC * FHW);
    int p0 = ylo * FW + xlo;
    int p1 = ylo * FW + xhi;
    int p2 = yhi * FW + xlo;
    int p3 = yhi * FW + xhi;
    if (nhwc)
        *oout = make_int4(bb + p0 * FC, bb + p1 * FC, bb + p2 * FC, bb + p3 * FC);
    else
        *oout = make_int4(bb + p0, bb + p1, bb + p2, bb + p3);
}

__device__ __forceinline__ float fixnum(float v)
{
    return (v == v && v <= 3.402823466e38f && v >= -3.402823466e38f) ? v : 1e-8f;
}

// ---------------------------------------------------------------------------
// NCHW f32 -> NHWC fp16 transpose. Tile = 64 ch x 32 px, block 256.
// grid (FHW/32, FC/64, N).
// LDS layout [px][swizzled ch]: 8-channel groups XOR-rotated by (px>>2)&7 so
// phase-1 b16 scatter writes hit all 32 banks (was {0,16} -> 8-way) while
// phase-2 keeps 16B-aligned ds_read_b128.
// ---------------------------------------------------------------------------
__global__ __launch_bounds__(256)
void transpose_f16_kernel(const float* __restrict__ in, __half* __restrict__ out)
{
    __shared__ __align__(16) __half tileT[32][72];   // stride 144 B
    int b   = blockIdx.z;
    int p0  = blockIdx.x * 32;
    int c0  = blockIdx.y * 64;
    int tid = threadIdx.x;

    const float* inb  = in  + (size_t)b * FC * FHW;
    __half*      outb = out + (size_t)b * FHW * FC;

#pragma unroll
    for (int k = 0; k < 2; ++k) {
        int chl = k * 32 + (tid >> 3);       // 0..63 local channel
        int px4 = (tid & 7) * 4;             // 0,4,..,28 local pixel
        float4 v = *(const float4*)(inb + (size_t)(c0 + chl) * FHW + p0 + px4);
        int g   = ((chl >> 3) ^ (px4 >> 2)) & 7;   // swizzled 8-ch group
        int col = (g << 3) | (chl & 7);
        tileT[px4 + 0][col] = __float2half(v.x);
        tileT[px4 + 1][col] = __float2half(v.y);
        tileT[px4 + 2][col] = __float2half(v.z);
        tileT[px4 + 3][col] = __float2half(v.w);
    }
    __syncthreads();

    int p = tid >> 3;                        // 0..31 pixel
    int q = tid & 7;                         // logical 8-ch group
    int g = (q ^ ((p >> 2) & 7));
    uint4 d = *(const uint4*)&tileT[p][g << 3];
    *(uint4*)(outb + (size_t)(p0 + p) * FC + c0 + q * 8) = d;
}

// ---------------------------------------------------------------------------
// Main kernel: grid (R, 2); block = 256 thr handles 128 channels of one RoI.
// Quarter-wave (16 lanes) owns one bin; lane owns 8 channels (16 B fp16 load
// per corner -> 256 B contiguous per group). Output staged fp16 in LDS
// [bin][ch], then dumped with coalesced float4 stores (25088 B per block,
// line-aligned -> no RMW).  LDS ~19.6 KB -> ~5 blocks/CU (~20 waves/CU).
// ---------------------------------------------------------------------------
__global__ __launch_bounds__(256, 5)
void roi_nhwc_f16_kernel(const __half* __restrict__ feat,
                         const float* __restrict__ rois,
                         float* __restrict__ out)
{
    __shared__ float4 s_w[NSAMP];
    __shared__ int4   s_o[NSAMP];
    __shared__ __align__(16) __half out_h[NBIN * OH_STRIDE];

    int r   = blockIdx.x;
    int c0  = blockIdx.y * 128;   // channel half
    int tid = threadIdx.x;

    const float* roi = rois + r * 6;
    if (tid < NSAMP) {
        float4 w; int4 o;
        compute_sample(roi, tid, true, &w, &o);
        s_w[tid] = w;
        s_o[tid] = o;
    }
    __syncthreads();

    int grp    = tid >> 4;        // 0..15 quarter-wave
    int lane16 = tid & 15;
    int ch8    = lane16 * 8;      // local channel offset 0..120

    const __half* fbase = feat + c0 + ch8;

    for (int bin = grp; bin < NBIN; bin += 16) {
        float acc[8];
#pragma unroll
        for (int i = 0; i < 8; ++i) acc[i] = 0.0f;

#pragma unroll
        for (int sub = 0; sub < 4; ++sub) {
            int s = bin * 4 + sub;
            float4 wt = s_w[s];
            int4   o  = s_o[s];
            uint4 u0 = *(const uint4*)(fbase + o.x);
            uint4 u1 = *(const uint4*)(fbase + o.y);
            uint4 u2 = *(const uint4*)(fbase + o.z);
            uint4 u3 = *(const uint4*)(fbase + o.w);
            const __half2* h0 = (const __half2*)&u0;
            const __half2* h1 = (const __half2*)&u1;
            const __half2* h2 = (const __half2*)&u2;
            const __half2* h3 = (const __half2*)&u3;
#pragma unroll
            for (int j = 0; j < 4; ++j) {
                float2 f0 = __half22float2(h0[j]);
                float2 f1 = __half22float2(h1[j]);
                float2 f2 = __half22float2(h2[j]);
                float2 f3 = __half22float2(h3[j]);
                acc[2 * j + 0] += wt.x * f0.x + wt.y * f1.x + wt.z * f2.x + wt.w * f3.x;
                acc[2 * j + 1] += wt.x * f0.y + wt.y * f1.y + wt.z * f2.y + wt.w * f3.y;
            }
        }
        __half2 hv[4];
#pragma unroll
        for (int j = 0; j < 4; ++j)
            hv[j] = __floats2half2_rn(acc[2 * j + 0], acc[2 * j + 1]);
        *(uint4*)&out_h[bin * OH_STRIDE + ch8] = *(const uint4*)hv;
    }
    __syncthreads();

    // Dump LDS [bin][ch_local] -> global [ch][bin], coalesced float4 stores.
    float* obase = out + (size_t)r * (FC * NBIN) + (size_t)blockIdx.y * (128 * NBIN);
    for (int v4 = tid; v4 < (128 * NBIN) / 4; v4 += 256) {
        int f0 = v4 * 4;
        float vals[4];
#pragma unroll
        for (int i = 0; i < 4; ++i) {
            int f = f0 + i;
            int c = f / NBIN;
            int b = f - c * NBIN;
            vals[i] = fixnum(__half2float(out_h[b * OH_STRIDE + c]));
        }
        *(float4*)(obase + f0) = make_float4(vals[0], vals[1], vals[2], vals[3]);
    }
}

// ---------------------------------------------------------------------------
// Fallback (ws too small): direct NCHW, correct but slow.
// ---------------------------------------------------------------------------
__global__ __launch_bounds__(256)
void roi_nchw_kernel(const float* __restrict__ feat,
                     const float* __restrict__ rois,
                     float* __restrict__ out)
{
    int r   = blockIdx.x;
    int tid = threadIdx.x;

    __shared__ float4 s_w[NSAMP];
    __shared__ int4   s_o[NSAMP];

    const float* roi = rois + r * 6;
    if (tid < NSAMP) {
        float4 w; int4 o;
        compute_sample(roi, tid, false, &w, &o);
        s_w[tid] = w;
        s_o[tid] = o;
    }
    __syncthreads();

    const float* fc = feat + (size_t)tid * FHW;
    float* obase = out + (size_t)r * (FC * NBIN) + (size_t)tid * NBIN;

    for (int bin = 0; bin < NBIN; ++bin) {
        float a = 0.0f;
#pragma unroll
        for (int k = 0; k < 4; ++k) {
            float4 w = s_w[bin * 4 + k];
            int4   o = s_o[bin * 4 + k];
            a += w.x * fc[o.x] + w.y * fc[o.y] + w.z * fc[o.z] + w.w * fc[o.w];
        }
        obase[bin] = fixnum(a);
    }
}

extern "C" void kernel_launch(void* const* d_in, const int* in_sizes, int n_in,
                              void* d_out, int out_size, void* d_ws, size_t ws_size,
                              hipStream_t stream)
{
    const float* feat = (const float*)d_in[0];
    const float* rois = (const float*)d_in[1];
    float* out = (float*)d_out;

    int R = in_sizes[1] / 6;
    int N = in_sizes[0] / (FC * FHW);
    size_t need = (size_t)in_sizes[0] * sizeof(__half);

    if (ws_size >= need) {
        __half* featT = (__half*)d_ws;
        dim3 tg(FHW / 32, FC / 64, N);
        transpose_f16_kernel<<<tg, 256, 0, stream>>>(feat, featT);
        dim3 g(R, 2, 1);
        roi_nhwc_f16_kernel<<<g, 256, 0, stream>>>(featT, rois, out);
    } else {
        roi_nchw_kernel<<<R, 256, 0, stream>>>(feat, rois, out);
    }
}

// Round 4
// 175.468 us; speedup vs baseline: 1.5531x; 1.5531x over previous
//
#include <hip/hip_runtime.h>
#include <hip/hip_fp16.h>

#define FH 200
#define FW 200
#define FHW 40000
#define FC 256
#define NBIN 49        // 7*7 output bins
#define NSAMP 196      // NBIN * 4 subsamples
#define OH_STRIDE 136  // out_h [bin][ch] stride in halves: 272 B, 16B-multiple

// ---------------------------------------------------------------------------
// Per-sample geometry: weights (pre-multiplied by valid-mask and 0.25 mean
// factor) and 4 bilinear-corner offsets (elements of the chosen layout).
// Matches the JAX reference (aligned coords, clamp-at-edge, valid in [-1,H]).
// ---------------------------------------------------------------------------
__device__ __forceinline__ void compute_sample(const float* __restrict__ roi,
                                               int s, bool nhwc,
                                               float4* wout, int4* oout)
{
    int   b  = (int)roi[0];
    float cw = roi[1] * 0.25f - 0.5f;
    float ch = roi[2] * 0.25f - 0.5f;
    float rw = fmaxf(roi[3] * 0.25f, 1.0f);
    float rh = fmaxf(roi[4] * 0.25f, 1.0f);
    float th = roi[5] * 0.017453292519943295f;   // pi/180
    float ct = cosf(th);
    float st = sinf(th);
    float bin_h = rh / 7.0f;
    float bin_w = rw / 7.0f;

    int bin = s >> 2;
    int sub = s & 3;
    int iy  = sub >> 1;
    int ix  = sub & 1;
    int ph  = bin / 7;
    int pw  = bin - ph * 7;

    float fy = 0.25f + 0.5f * (float)iy;  // frac = {0.25, 0.75}
    float fx = 0.25f + 0.5f * (float)ix;
    float yy = -rh * 0.5f + ((float)ph + fy) * bin_h;
    float xx = -rw * 0.5f + ((float)pw + fx) * bin_w;
    float y  = yy * ct - xx * st + ch;
    float x  = yy * st + xx * ct + cw;

    bool valid = (y >= -1.0f) && (y <= (float)FH) && (x >= -1.0f) && (x <= (float)FW);
    y = fmaxf(y, 0.0f);
    x = fmaxf(x, 0.0f);
    int y0 = (int)floorf(y);
    int x0 = (int)floorf(x);
    bool cy = (y0 >= FH - 1);
    bool cx = (x0 >= FW - 1);
    int ylo = cy ? (FH - 1) : y0;
    int yhi = cy ? (FH - 1) : (y0 + 1);
    int xlo = cx ? (FW - 1) : x0;
    int xhi = cx ? (FW - 1) : (x0 + 1);
    float ly = cy ? 0.0f : (y - (float)y0);
    float lx = cx ? 0.0f : (x - (float)x0);
    float hy = 1.0f - ly;
    float hx = 1.0f - lx;
    float m  = valid ? 0.25f : 0.0f;   // fold valid-mask + mean(4 samples)

    *wout = make_float4(hy * hx * m, hy * lx * m, ly * hx * m, ly * lx * m);

    int bb = b * (FC * FHW);
    int p0 = ylo * FW + xlo;
    int p1 = ylo * FW + xhi;
    int p2 = yhi * FW + xlo;
    int p3 = yhi * FW + xhi;
    if (nhwc)
        *oout = make_int4(bb + p0 * FC, bb + p1 * FC, bb + p2 * FC, bb + p3 * FC);
    else
        *oout = make_int4(bb + p0, bb + p1, bb + p2, bb + p3);
}

__device__ __forceinline__ float fixnum(float v)
{
    return (v == v && v <= 3.402823466e38f && v >= -3.402823466e38f) ? v : 1e-8f;
}

// ---------------------------------------------------------------------------
// NCHW f32 -> NHWC fp16 transpose. Tile = 64 ch x 32 px, block 256.
// grid (FHW/32, FC/64, N).
// LDS layout [px][swizzled ch]: 8-channel groups XOR-rotated by (px>>2)&7 so
// phase-1 b16 scatter writes hit all 32 banks while phase-2 keeps 16B-aligned
// ds_read_b128.
// ---------------------------------------------------------------------------
__global__ __launch_bounds__(256)
void transpose_f16_kernel(const float* __restrict__ in, __half* __restrict__ out)
{
    __shared__ __align__(16) __half tileT[32][72];   // stride 144 B
    int b   = blockIdx.z;
    int p0  = blockIdx.x * 32;
    int c0  = blockIdx.y * 64;
    int tid = threadIdx.x;

    const float* inb  = in  + (size_t)b * FC * FHW;
    __half*      outb = out + (size_t)b * FHW * FC;

#pragma unroll
    for (int k = 0; k < 2; ++k) {
        int chl = k * 32 + (tid >> 3);       // 0..63 local channel
        int px4 = (tid & 7) * 4;             // 0,4,..,28 local pixel
        float4 v = *(const float4*)(inb + (size_t)(c0 + chl) * FHW + p0 + px4);
        int g   = ((chl >> 3) ^ (px4 >> 2)) & 7;   // swizzled 8-ch group
        int col = (g << 3) | (chl & 7);
        tileT[px4 + 0][col] = __float2half(v.x);
        tileT[px4 + 1][col] = __float2half(v.y);
        tileT[px4 + 2][col] = __float2half(v.z);
        tileT[px4 + 3][col] = __float2half(v.w);
    }
    __syncthreads();

    int p = tid >> 3;                        // 0..31 pixel
    int q = tid & 7;                         // logical 8-ch group
    int g = (q ^ ((p >> 2) & 7));
    uint4 d = *(const uint4*)&tileT[p][g << 3];
    *(uint4*)(outb + (size_t)(p0 + p) * FC + c0 + q * 8) = d;
}

// ---------------------------------------------------------------------------
// Main kernel: grid (R, 2); block = 256 thr handles 128 channels of one RoI.
// Quarter-wave (16 lanes) owns one bin; lane owns 8 channels (16 B fp16 load
// per corner -> 256 B contiguous per group). Output staged fp16 in LDS
// [bin][ch], then dumped with coalesced float4 stores (25088 B per block,
// line-aligned -> no RMW).
// NOTE: no min-waves in __launch_bounds__ — R3's (256,5) clamped VGPRs to 48
// and spilled ~290 MB to scratch (WRITE_SIZE 341 MB). Natural VGPR ~88 gives
// 5 waves/SIMD anyway.
// ---------------------------------------------------------------------------
__global__ __launch_bounds__(256)
void roi_nhwc_f16_kernel(const __half* __restrict__ feat,
                         const float* __restrict__ rois,
                         float* __restrict__ out)
{
    __shared__ float4 s_w[NSAMP];
    __shared__ int4   s_o[NSAMP];
    __shared__ __align__(16) __half out_h[NBIN * OH_STRIDE];

    int r   = blockIdx.x;
    int c0  = blockIdx.y * 128;   // channel half
    int tid = threadIdx.x;

    const float* roi = rois + r * 6;
    if (tid < NSAMP) {
        float4 w; int4 o;
        compute_sample(roi, tid, true, &w, &o);
        s_w[tid] = w;
        s_o[tid] = o;
    }
    __syncthreads();

    int grp    = tid >> 4;        // 0..15 quarter-wave
    int lane16 = tid & 15;
    int ch8    = lane16 * 8;      // local channel offset 0..120

    const __half* fbase = feat + c0 + ch8;

    for (int bin = grp; bin < NBIN; bin += 16) {
        float acc[8];
#pragma unroll
        for (int i = 0; i < 8; ++i) acc[i] = 0.0f;

#pragma unroll
        for (int sub = 0; sub < 4; ++sub) {
            int s = bin * 4 + sub;
            float4 wt = s_w[s];
            int4   o  = s_o[s];
            uint4 u0 = *(const uint4*)(fbase + o.x);
            uint4 u1 = *(const uint4*)(fbase + o.y);
            uint4 u2 = *(const uint4*)(fbase + o.z);
            uint4 u3 = *(const uint4*)(fbase + o.w);
            const __half2* h0 = (const __half2*)&u0;
            const __half2* h1 = (const __half2*)&u1;
            const __half2* h2 = (const __half2*)&u2;
            const __half2* h3 = (const __half2*)&u3;
#pragma unroll
            for (int j = 0; j < 4; ++j) {
                float2 f0 = __half22float2(h0[j]);
                float2 f1 = __half22float2(h1[j]);
                float2 f2 = __half22float2(h2[j]);
                float2 f3 = __half22float2(h3[j]);
                acc[2 * j + 0] += wt.x * f0.x + wt.y * f1.x + wt.z * f2.x + wt.w * f3.x;
                acc[2 * j + 1] += wt.x * f0.y + wt.y * f1.y + wt.z * f2.y + wt.w * f3.y;
            }
        }
        __half2 hv[4];
#pragma unroll
        for (int j = 0; j < 4; ++j)
            hv[j] = __floats2half2_rn(acc[2 * j + 0], acc[2 * j + 1]);
        *(uint4*)&out_h[bin * OH_STRIDE + ch8] = *(const uint4*)hv;
    }
    __syncthreads();

    // Dump LDS [bin][ch_local] -> global [ch][bin], coalesced float4 stores.
    float* obase = out + (size_t)r * (FC * NBIN) + (size_t)blockIdx.y * (128 * NBIN);
    for (int v4 = tid; v4 < (128 * NBIN) / 4; v4 += 256) {
        int f0 = v4 * 4;
        float vals[4];
#pragma unroll
        for (int i = 0; i < 4; ++i) {
            int f = f0 + i;
            int c = f / NBIN;
            int b = f - c * NBIN;
            vals[i] = fixnum(__half2float(out_h[b * OH_STRIDE + c]));
        }
        *(float4*)(obase + f0) = make_float4(vals[0], vals[1], vals[2], vals[3]);
    }
}

// ---------------------------------------------------------------------------
// Fallback (ws too small): direct NCHW, correct but slow.
// ---------------------------------------------------------------------------
__global__ __launch_bounds__(256)
void roi_nchw_kernel(const float* __restrict__ feat,
                     const float* __restrict__ rois,
                     float* __restrict__ out)
{
    int r   = blockIdx.x;
    int tid = threadIdx.x;

    __shared__ float4 s_w[NSAMP];
    __shared__ int4   s_o[NSAMP];

    const float* roi = rois + r * 6;
    if (tid < NSAMP) {
        float4 w; int4 o;
        compute_sample(roi, tid, false, &w, &o);
        s_w[tid] = w;
        s_o[tid] = o;
    }
    __syncthreads();

    const float* fc = feat + (size_t)tid * FHW;
    float* obase = out + (size_t)r * (FC * NBIN) + (size_t)tid * NBIN;

    for (int bin = 0; bin < NBIN; ++bin) {
        float a = 0.0f;
#pragma unroll
        for (int k = 0; k < 4; ++k) {
            float4 w = s_w[bin * 4 + k];
            int4   o = s_o[bin * 4 + k];
            a += w.x * fc[o.x] + w.y * fc[o.y] + w.z * fc[o.z] + w.w * fc[o.w];
        }
        obase[bin] = fixnum(a);
    }
}

extern "C" void kernel_launch(void* const* d_in, const int* in_sizes, int n_in,
                              void* d_out, int out_size, void* d_ws, size_t ws_size,
                              hipStream_t stream)
{
    const float* feat = (const float*)d_in[0];
    const float* rois = (const float*)d_in[1];
    float* out = (float*)d_out;

    int R = in_sizes[1] / 6;
    int N = in_sizes[0] / (FC * FHW);
    size_t need = (size_t)in_sizes[0] * sizeof(__half);

    if (ws_size >= need) {
        __half* featT = (__half*)d_ws;
        dim3 tg(FHW / 32, FC / 64, N);
        transpose_f16_kernel<<<tg, 256, 0, stream>>>(feat, featT);
        dim3 g(R, 2, 1);
        roi_nhwc_f16_kernel<<<g, 256, 0, stream>>>(featT, rois, out);
    } else {
        roi_nchw_kernel<<<R, 256, 0, stream>>>(feat, rois, out);
    }
}